// Round 6
// baseline (1800.533 us; speedup 1.0000x reference)
//
#include <hip/hip_runtime.h>
#include <math.h>

#define NL 4
#define DM 1024
#define NH 8
#define HD 128
#define BB 8
#define LL 512
#define MM (BB*LL)      // 4096 rows
#define PEN (2*LL)      // 1024 pe rows
#define QT 64           // q rows per attn block
#define KT 32           // k tile
#define NKT (LL/KT)     // 16

typedef __attribute__((ext_vector_type(8))) __bf16 bf16x8;
typedef __attribute__((ext_vector_type(4))) float f32x4;

// ---------------- helpers ----------------
__device__ __forceinline__ unsigned short f2b(float f) {   // RNE f32->bf16
  unsigned int u = __float_as_uint(f);
  u = (u + 0x7FFFu + ((u >> 16) & 1u)) >> 16;
  return (unsigned short)u;
}
__device__ __forceinline__ float b2f(unsigned short s) {
  return __uint_as_float(((unsigned int)s) << 16);
}
__device__ __forceinline__ void glds16(const void* g, void* l) {
  __builtin_amdgcn_global_load_lds(
      (const __attribute__((address_space(1))) unsigned int*)g,
      (__attribute__((address_space(3))) unsigned int*)l, 16, 0, 0);
}
union U8 { unsigned short s[8]; bf16x8 v; };
// trunc-hi / RNE-lo split of 8 floats
__device__ __forceinline__ void split8(const float4& a, const float4& b,
                                       bf16x8& h, bf16x8& l) {
  float x[8] = {a.x,a.y,a.z,a.w,b.x,b.y,b.z,b.w};
  U8 uh, ul;
#pragma unroll
  for (int e = 0; e < 8; ++e) {
    unsigned u = __float_as_uint(x[e]);
    uh.s[e] = (unsigned short)(u >> 16);
    ul.s[e] = f2b(x[e] - __uint_as_float(u & 0xffff0000u));
  }
  h = uh.v; l = ul.v;
}

// -------- relative position embedding (RNE hi + RNE residual lo) ----------
__global__ __launch_bounds__(256) void pe_kernel(unsigned short* __restrict__ peh,
                                                 unsigned short* __restrict__ pel) {
  int idx = blockIdx.x * 256 + threadIdx.x;
  if (idx >= PEN * HD) return;
  int p = idx / HD, j = idx % HD;
  int tt = (j < 64) ? j : (j - 64);
  float invf = expf((float)tt * (-9.210340371976184f / 63.0f));
  float ang = (float)(p - LL) * invf;
  float v = (j < 64) ? sinf(ang) : cosf(ang);
  unsigned short h = f2b(v);
  peh[idx] = h;
  pel[idx] = f2b(v - b2f(h));
}

// ---------------- d2[n][p] = (rw[n]-rr[n]) . pe[p] ----------------
__global__ __launch_bounds__(256) void d2_kernel(const float* __restrict__ rrb,
                                                 const float* __restrict__ rwb,
                                                 const unsigned short* __restrict__ peh,
                                                 const unsigned short* __restrict__ pel,
                                                 float* __restrict__ d2) {
  int idx = blockIdx.x * 256 + threadIdx.x;
  if (idx >= NH * PEN) return;
  int n = idx / PEN, p = idx % PEN;
  float s = 0.f;
  for (int d = 0; d < HD; ++d) {
    float pv = b2f(peh[p*HD + d]) + b2f(pel[p*HD + d]);
    s += (rwb[n*HD + d] - rrb[n*HD + d]) * pv;
  }
  d2[idx] = s;
}

// ---------------- split f32 -> (hi,lo) bf16 pair, RNE ----------------
__global__ __launch_bounds__(256) void split_kernel(const float* __restrict__ in,
                                                    unsigned short* __restrict__ hi,
                                                    unsigned short* __restrict__ lo,
                                                    int n) {
  int i = (blockIdx.x * 256 + threadIdx.x) * 4;
  if (i >= n) return;
  float4 v = *(const float4*)&in[i];
  float x[4] = {v.x, v.y, v.z, v.w};
  ushort4 h4, l4;
  unsigned short* hp = (unsigned short*)&h4;
  unsigned short* lp = (unsigned short*)&l4;
#pragma unroll
  for (int e = 0; e < 4; ++e) {
    unsigned short h = f2b(x[e]);
    hp[e] = h;
    lp[e] = f2b(x[e] - b2f(h));
  }
  *(ushort4*)&hi[i] = h4;
  *(ushort4*)&lo[i] = l4;
}

// ---------------- split-bf16 MFMA GEMM: C = A[M][K] @ Bw[N][K]^T -----------
template<bool FFN>
__global__ __launch_bounds__(256) void gemm_mfma(
    const unsigned short* __restrict__ Ah, const unsigned short* __restrict__ Al,
    const float* __restrict__ Bw, const float* __restrict__ bias,
    float* __restrict__ C, int N, int K, int ldc) {
  __shared__ __align__(16) unsigned short AsH[128*32];
  __shared__ __align__(16) unsigned short AsL[128*32];
  __shared__ __align__(16) unsigned short BsH[128*40];
  __shared__ __align__(16) unsigned short BsL[128*40];
  const int t = threadIdx.x;
  const int w = t >> 6, l = t & 63;
  const int bm = blockIdx.y * 128, bn = blockIdx.x * 128;
  const int wr = (w >> 1) * 64, wc = (w & 1) * 64;

  const unsigned short* Ahb = Ah + (size_t)(bm + (t >> 2)) * K + (t & 3) * 8;
  const unsigned short* Alb = Al + (size_t)(bm + (t >> 2)) * K + (t & 3) * 8;
  unsigned short* AsHw0 = &AsH[w * 512];
  unsigned short* AsHw1 = &AsH[2048 + w * 512];
  unsigned short* AsLw0 = &AsL[w * 512];
  unsigned short* AsLw1 = &AsL[2048 + w * 512];

  const int brow = t >> 1, bhalf = (t & 1) * 16;
  const float* Bb = Bw + (size_t)(bn + brow) * K + bhalf;

  f32x4 acc[4][4] = {};
  const int lm = l & 15;
  const int lk = (l >> 4) * 8;

  for (int k0 = 0; k0 < K; k0 += 32) {
    float4 bv[4];
#pragma unroll
    for (int c = 0; c < 4; ++c)
      bv[c] = *(const float4*)(Bb + k0 + c*4);
    glds16(Ahb + k0,                 AsHw0);
    glds16(Ahb + (size_t)64*K + k0,  AsHw1);
    glds16(Alb + k0,                 AsLw0);
    glds16(Alb + (size_t)64*K + k0,  AsLw1);
#pragma unroll
    for (int c = 0; c < 4; ++c) {
      float xs[4] = {bv[c].x, bv[c].y, bv[c].z, bv[c].w};
      ushort4 h4, l4;
      unsigned short* hp = (unsigned short*)&h4;
      unsigned short* lp = (unsigned short*)&l4;
#pragma unroll
      for (int e = 0; e < 4; ++e) {
        unsigned u = __float_as_uint(xs[e]);
        hp[e] = (unsigned short)(u >> 16);
        float r = xs[e] - __uint_as_float(u & 0xffff0000u);
        lp[e] = (unsigned short)(__float_as_uint(r) >> 16);
      }
      *(ushort4*)&BsH[brow*40 + bhalf + c*4] = h4;
      *(ushort4*)&BsL[brow*40 + bhalf + c*4] = l4;
    }
    __syncthreads();

    bf16x8 afh[4], afl[4], bfh[4], bfl[4];
#pragma unroll
    for (int i = 0; i < 4; ++i) {
      afh[i] = *(const bf16x8*)&AsH[(wr + i*16 + lm) * 32 + lk];
      afl[i] = *(const bf16x8*)&AsL[(wr + i*16 + lm) * 32 + lk];
    }
#pragma unroll
    for (int j = 0; j < 4; ++j) {
      bfh[j] = *(const bf16x8*)&BsH[(wc + j*16 + lm) * 40 + lk];
      bfl[j] = *(const bf16x8*)&BsL[(wc + j*16 + lm) * 40 + lk];
    }
#pragma unroll
    for (int i = 0; i < 4; ++i)
#pragma unroll
      for (int j = 0; j < 4; ++j) {
        acc[i][j] = __builtin_amdgcn_mfma_f32_16x16x32_bf16(afh[i], bfh[j], acc[i][j], 0, 0, 0);
        acc[i][j] = __builtin_amdgcn_mfma_f32_16x16x32_bf16(afh[i], bfl[j], acc[i][j], 0, 0, 0);
        acc[i][j] = __builtin_amdgcn_mfma_f32_16x16x32_bf16(afl[i], bfh[j], acc[i][j], 0, 0, 0);
      }
    __syncthreads();
  }

  const int cr = (l >> 4) * 4;
#pragma unroll
  for (int i = 0; i < 4; ++i) {
#pragma unroll
    for (int j = 0; j < 4; ++j) {
      int row = bm + wr + i*16 + cr;
      int col = bn + wc + j*16 + lm;
      float bvl = FFN ? bias[col] : 0.f;
      f32x4 a = acc[i][j];
#pragma unroll
      for (int r4 = 0; r4 < 4; ++r4) {
        float v = a[r4];
        if (FFN) v = fmaxf(v + bvl, 0.f);
        C[(size_t)(row + r4) * ldc + col] = v;
      }
    }
  }
}

// ================= MFMA fused relative attention (v3) =================
// grid (LL/QT=8, NH, BB), 256 threads = 4 waves; wave w owns q-rows
// [q0+16w, q0+16w+16). logit = qa.k + qa.pe[k-q+512] + d2[n][k-q+512].
// ALL MFMA paths 3-pass split-bf16 (round-4 numerics, absmax 0.031).
// pe fragments streamed from global (L2-resident 512KB table) - no pe LDS.
// LDS 52KB -> 3 blocks/CU. Ks/Vt/Ps XOR 16B-slot swizzled (verified algebra).
__global__ __launch_bounds__(256, 3) void attn_mfma(
    const float* __restrict__ qv,           // [MM][2048] f32 (q | v)
    const unsigned short* __restrict__ khp, // keys hi  [MM][1024]
    const unsigned short* __restrict__ klp, // keys lo
    const unsigned short* __restrict__ pehp,// [1024][128] bf16 hi
    const unsigned short* __restrict__ pelp,// [1024][128] bf16 lo
    const float* __restrict__ rrb,          // [NH][128] layer slice
    const int*   __restrict__ mask,         // [BB][LL]
    const float* __restrict__ d2p,          // [NH][1024]
    float* __restrict__ outp)               // = qv (q-half, stride 2048)
{
  __shared__ __align__(16) unsigned short KsH[KT*128];   // 8 KB, swz ^(row&7)
  __shared__ __align__(16) unsigned short KsL[KT*128];   // 8 KB
  __shared__ __align__(16) unsigned short VtH[HD*32];    // 8 KB, swz ^(dim&3)
  __shared__ __align__(16) unsigned short VtL[HD*32];    // 8 KB
  __shared__ float Bsc[4][16*48];                        // 12 KB
  __shared__ __align__(16) unsigned short PsH[4][16*32]; // 4 KB, swz ^(qi&3)
  __shared__ __align__(16) unsigned short PsL[4][16*32]; // 4 KB
  // total 52 KB

  const int q0 = blockIdx.x * QT;
  const int n  = blockIdx.y, b = blockIdx.z;
  const int t  = threadIdx.x;
  const int w  = t >> 6, l = t & 63;
  const int lm = l & 15, lg = l >> 4;
  const int q0w = q0 + w*16;
  const int r8 = t >> 3, s8 = t & 7;        // staging: row, 16-short seg
  const int vr0 = t >> 5, vd4 = (t & 31)*4; // V staging

  // ---- qa A-frags in registers (split hi/lo) ----
  bf16x8 qah[4], qal[4];
  {
    size_t qrow = (size_t)(b*LL + q0w + lm) * (2*DM) + (size_t)n*HD;
#pragma unroll
    for (int c = 0; c < 4; ++c) {
      int d0 = c*32 + lg*8;
      float4 x1 = *(const float4*)&qv[qrow + d0];
      float4 x2 = *(const float4*)&qv[qrow + d0 + 4];
      float4 r1 = *(const float4*)&rrb[n*HD + d0];
      float4 r2 = *(const float4*)&rrb[n*HD + d0 + 4];
      float4 a = {x1.x+r1.x, x1.y+r1.y, x1.z+r1.z, x1.w+r1.w};
      float4 bq = {x2.x+r2.x, x2.y+r2.y, x2.z+r2.z, x2.w+r2.w};
      split8(a, bq, qah[c], qal[c]);
    }
  }

  // ---- prologue staging: K/V tile 0 ----
  {
    size_t krow = (size_t)(b*LL + r8)*DM + (size_t)n*HD + s8*16;
    int sx = r8 & 7;
    *(uint4*)&KsH[r8*128 + ((2*s8)^sx)*8]   = *(const uint4*)&khp[krow];
    *(uint4*)&KsH[r8*128 + ((2*s8+1)^sx)*8] = *(const uint4*)&khp[krow + 8];
    *(uint4*)&KsL[r8*128 + ((2*s8)^sx)*8]   = *(const uint4*)&klp[krow];
    *(uint4*)&KsL[r8*128 + ((2*s8+1)^sx)*8] = *(const uint4*)&klp[krow + 8];
#pragma unroll
    for (int i = 0; i < 4; ++i) {
      int vrow = vr0 + 8*i;
      float4 vv = *(const float4*)&qv[(size_t)(b*LL + vrow)*(2*DM) + DM + n*HD + vd4];
      float xs[4] = {vv.x, vv.y, vv.z, vv.w};
#pragma unroll
      for (int e = 0; e < 4; ++e) {
        int dim = vd4 + e;
        unsigned u = __float_as_uint(xs[e]);
        int idx = dim*32 + (((vrow>>3)^(dim&3))*8) + (vrow&7);
        VtH[idx] = (unsigned short)(u >> 16);
        VtL[idx] = f2b(xs[e] - __uint_as_float(u & 0xffff0000u));
      }
    }
  }
  __syncthreads();

  float m_run[4] = {-3.0e38f, -3.0e38f, -3.0e38f, -3.0e38f};
  float l_run[4] = {0.f, 0.f, 0.f, 0.f};
  f32x4 accO[8] = {};

  for (int kt = 0; kt < NKT; ++kt) {
    const int k0 = kt * KT;
    const int base_w = k0 - q0w + 497;

    // ---- A) prefetch K/V tile kt+1 into registers ----
    uint4 kxh0, kxh1, kxl0, kxl1;
    float4 vx[4];
    const bool pf = kt < NKT-1;
    if (pf) {
      size_t krow = (size_t)(b*LL + k0 + KT + r8)*DM + (size_t)n*HD + s8*16;
      kxh0 = *(const uint4*)&khp[krow];     kxh1 = *(const uint4*)&khp[krow + 8];
      kxl0 = *(const uint4*)&klp[krow];     kxl1 = *(const uint4*)&klp[krow + 8];
#pragma unroll
      for (int i = 0; i < 4; ++i)
        vx[i] = *(const float4*)&qv[(size_t)(b*LL + k0 + KT + vr0 + 8*i)*(2*DM) + DM + n*HD + vd4];
    }

    // ---- B) compute tile kt ----
    // d2 + mask (global, L2-hot)
    float d2v[3];
#pragma unroll
    for (int jt = 0; jt < 3; ++jt) {
      int di = base_w + jt*16 + lm;
      di = di > PEN-1 ? PEN-1 : di;
      d2v[jt] = d2p[n*PEN + di];
    }
    const int msk0 = mask[b*LL + k0 + lm];
    const int msk1 = mask[b*LL + k0 + 16 + lm];

    // pe-term MFMA (3-pass, B-frags streamed from global/L2) -> Bsc (+d2)
#pragma unroll
    for (int jt = 0; jt < 3; ++jt) {
      int prow = base_w + jt*16 + lm;
      prow = prow > PEN-1 ? PEN-1 : prow;     // row 1024 edge: col 47, never read
      const unsigned short* pb = pehp + (size_t)prow*HD + lg*8;
      const unsigned short* ql = pelp + (size_t)prow*HD + lg*8;
      bf16x8 ph[4], pl[4];
#pragma unroll
      for (int c = 0; c < 4; ++c) {
        ph[c] = *(const bf16x8*)(pb + c*32);
        pl[c] = *(const bf16x8*)(ql + c*32);
      }
      f32x4 accB = {};
#pragma unroll
      for (int c = 0; c < 4; ++c) {
        accB = __builtin_amdgcn_mfma_f32_16x16x32_bf16(qah[c], ph[c], accB, 0, 0, 0);
        accB = __builtin_amdgcn_mfma_f32_16x16x32_bf16(qah[c], pl[c], accB, 0, 0, 0);
        accB = __builtin_amdgcn_mfma_f32_16x16x32_bf16(qal[c], ph[c], accB, 0, 0, 0);
      }
#pragma unroll
      for (int r = 0; r < 4; ++r)
        Bsc[w][(lg*4 + r)*48 + jt*16 + lm] = accB[r] + d2v[jt];
    }
    asm volatile("s_waitcnt lgkmcnt(0)" ::: "memory");
    __builtin_amdgcn_sched_barrier(0);

    // AC MFMA (3-pass, full precision)
    f32x4 accA[2] = {};
#pragma unroll
    for (int tt = 0; tt < 2; ++tt)
#pragma unroll
      for (int c = 0; c < 4; ++c) {
        const int krow = tt*16 + lm, sx = krow & 7;
        bf16x8 kfh = *(const bf16x8*)&KsH[krow*128 + (((c*4+lg)^sx)*8)];
        bf16x8 kfl = *(const bf16x8*)&KsL[krow*128 + (((c*4+lg)^sx)*8)];
        accA[tt] = __builtin_amdgcn_mfma_f32_16x16x32_bf16(qah[c], kfh, accA[tt], 0, 0, 0);
        accA[tt] = __builtin_amdgcn_mfma_f32_16x16x32_bf16(qah[c], kfl, accA[tt], 0, 0, 0);
        accA[tt] = __builtin_amdgcn_mfma_f32_16x16x32_bf16(qal[c], kfh, accA[tt], 0, 0, 0);
      }

    // softmax in C-layout (rows lg*4+r, cols lm+16t)
    float s[2][4];
#pragma unroll
    for (int tt = 0; tt < 2; ++tt)
#pragma unroll
      for (int r = 0; r < 4; ++r) {
        int qi = lg*4 + r;
        int kc = tt*16 + lm;
        int j  = kc - qi + 15;
        float v = accA[tt][r] + Bsc[w][qi*48 + j];
        s[tt][r] = ((tt ? msk1 : msk0) == 0) ? -1e30f : v;
      }
    float sc4[4];
#pragma unroll
    for (int r = 0; r < 4; ++r) {
      float mt = fmaxf(s[0][r], s[1][r]);
      mt = fmaxf(mt, __shfl_xor(mt, 1));
      mt = fmaxf(mt, __shfl_xor(mt, 2));
      mt = fmaxf(mt, __shfl_xor(mt, 4));
      mt = fmaxf(mt, __shfl_xor(mt, 8));
      float mn = fmaxf(m_run[r], mt);
      sc4[r] = __expf(m_run[r] - mn);
      m_run[r] = mn;
      float p0 = __expf(s[0][r] - mn);
      float p1 = __expf(s[1][r] - mn);
      s[0][r] = p0; s[1][r] = p1;
      float la = p0 + p1;
      la += __shfl_xor(la, 1);
      la += __shfl_xor(la, 2);
      la += __shfl_xor(la, 4);
      la += __shfl_xor(la, 8);
      l_run[r] = l_run[r]*sc4[r] + la;
    }
#pragma unroll
    for (int j8 = 0; j8 < 8; ++j8)
#pragma unroll
      for (int r = 0; r < 4; ++r)
        accO[j8][r] *= sc4[r];

    // P -> split bf16 in LDS (trunc hi / RNE lo; A-frag layout, swizzled)
#pragma unroll
    for (int tt = 0; tt < 2; ++tt)
#pragma unroll
      for (int r = 0; r < 4; ++r) {
        int qi = lg*4 + r, kc = tt*16 + lm;
        float p = s[tt][r];
        unsigned u = __float_as_uint(p);
        int idx = qi*32 + (((kc>>3)^(qi&3))*8) + (kc&7);
        PsH[w][idx] = (unsigned short)(u >> 16);
        PsL[w][idx] = f2b(p - __uint_as_float(u & 0xffff0000u));
      }
    asm volatile("s_waitcnt lgkmcnt(0)" ::: "memory");
    __builtin_amdgcn_sched_barrier(0);

    // PV MFMA (3-pass)
    {
      bf16x8 pah = *(const bf16x8*)&PsH[w][lm*32 + ((lg^(lm&3))*8)];
      bf16x8 pal = *(const bf16x8*)&PsL[w][lm*32 + ((lg^(lm&3))*8)];
#pragma unroll
      for (int j8 = 0; j8 < 8; ++j8) {
        const int dim = j8*16 + lm;
        bf16x8 vfh = *(const bf16x8*)&VtH[dim*32 + ((lg^(dim&3))*8)];
        bf16x8 vfl = *(const bf16x8*)&VtL[dim*32 + ((lg^(dim&3))*8)];
        accO[j8] = __builtin_amdgcn_mfma_f32_16x16x32_bf16(pah, vfh, accO[j8], 0, 0, 0);
        accO[j8] = __builtin_amdgcn_mfma_f32_16x16x32_bf16(pah, vfl, accO[j8], 0, 0, 0);
        accO[j8] = __builtin_amdgcn_mfma_f32_16x16x32_bf16(pal, vfh, accO[j8], 0, 0, 0);
      }
    }

    __syncthreads();   // all waves done reading Ks/Vt

    // ---- C) write staged tile kt+1 ----
    if (pf) {
      int sx = r8 & 7;
      *(uint4*)&KsH[r8*128 + ((2*s8)^sx)*8]   = kxh0;
      *(uint4*)&KsH[r8*128 + ((2*s8+1)^sx)*8] = kxh1;
      *(uint4*)&KsL[r8*128 + ((2*s8)^sx)*8]   = kxl0;
      *(uint4*)&KsL[r8*128 + ((2*s8+1)^sx)*8] = kxl1;
#pragma unroll
      for (int i = 0; i < 4; ++i) {
        int vrow = vr0 + 8*i;
        float xs[4] = {vx[i].x, vx[i].y, vx[i].z, vx[i].w};
#pragma unroll
        for (int e = 0; e < 4; ++e) {
          int dim = vd4 + e;
          unsigned u = __float_as_uint(xs[e]);
          int idx = dim*32 + (((vrow>>3)^(dim&3))*8) + (vrow&7);
          VtH[idx] = (unsigned short)(u >> 16);
          VtL[idx] = f2b(xs[e] - __uint_as_float(u & 0xffff0000u));
        }
      }
    }
    __syncthreads();
  }

  // ---- epilogue: O / l  ->  q-half of qv ----
  float inv[4];
#pragma unroll
  for (int r = 0; r < 4; ++r) inv[r] = 1.0f / l_run[r];
#pragma unroll
  for (int j8 = 0; j8 < 8; ++j8)
#pragma unroll
    for (int r = 0; r < 4; ++r)
      outp[(size_t)(b*LL + q0w + lg*4 + r)*(2*DM) + n*HD + j8*16 + lm] = accO[j8][r] * inv[r];
}

// ------- residual add + layernorm (+ split hi/lo bf16 for next GEMM) -------
__global__ __launch_bounds__(256) void add_ln_kernel(
    const float* __restrict__ y, int ys,
    const float* __restrict__ res,
    const float* __restrict__ g, const float* __restrict__ bt,
    float* __restrict__ out,
    unsigned short* __restrict__ ohi, unsigned short* __restrict__ olo)
{
  const int r = blockIdx.x, t = threadIdx.x;
  float4 v = *(const float4*)&y[(size_t)r*ys + t*4];
  float4 w = *(const float4*)&res[(size_t)r*DM + t*4];
  float4 s = {v.x+w.x, v.y+w.y, v.z+w.z, v.w+w.w};
  float sum = s.x + s.y + s.z + s.w;
  float ssq = s.x*s.x + s.y*s.y + s.z*s.z + s.w*s.w;
#pragma unroll
  for (int off = 32; off >= 1; off >>= 1) {
    sum += __shfl_down(sum, off);
    ssq += __shfl_down(ssq, off);
  }
  __shared__ float red[8];
  int wid = t >> 6;
  if ((t & 63) == 0) { red[wid] = sum; red[wid+4] = ssq; }
  __syncthreads();
  float totS = red[0] + red[1] + red[2] + red[3];
  float totQ = red[4] + red[5] + red[6] + red[7];
  float mu  = totS * (1.0f/DM);
  float var = totQ * (1.0f/DM) - mu*mu;
  float inv = rsqrtf(var + 1e-5f);
  float4 gg = *(const float4*)&g[t*4];
  float4 bb = *(const float4*)&bt[t*4];
  float4 o;
  o.x = (s.x - mu)*inv*gg.x + bb.x;
  o.y = (s.y - mu)*inv*gg.y + bb.y;
  o.z = (s.z - mu)*inv*gg.z + bb.z;
  o.w = (s.w - mu)*inv*gg.w + bb.w;
  *(float4*)&out[(size_t)r*DM + t*4] = o;
  float xs[4] = {o.x, o.y, o.z, o.w};
  ushort4 h4, l4;
  unsigned short* hp = (unsigned short*)&h4;
  unsigned short* lp = (unsigned short*)&l4;
#pragma unroll
  for (int e = 0; e < 4; ++e) {
    unsigned short h = f2b(xs[e]);
    hp[e] = h;
    lp[e] = f2b(xs[e] - b2f(h));
  }
  *(ushort4*)&ohi[(size_t)r*DM + t*4] = h4;
  *(ushort4*)&olo[(size_t)r*DM + t*4] = l4;
}

extern "C" void kernel_launch(void* const* d_in, const int* in_sizes, int n_in,
                              void* d_out, int out_size, void* d_ws, size_t ws_size,
                              hipStream_t stream) {
  const float* x    = (const float*)d_in[0];
  const int*   mask = (const int*)d_in[1];
  const float* qv_w = (const float*)d_in[2];
  const float* rrb  = (const float*)d_in[3];
  const float* rwb  = (const float*)d_in[4];
  const float* ln1g = (const float*)d_in[5];
  const float* ln1b = (const float*)d_in[6];
  const float* ffnw = (const float*)d_in[7];
  const float* ffnb = (const float*)d_in[8];
  const float* ln2g = (const float*)d_in[9];
  const float* ln2b = (const float*)d_in[10];

  float* h  = (float*)d_out;                      // [MM][DM] hidden (f32)
  unsigned short* peh = (unsigned short*)d_ws;    // 131072 sh
  unsigned short* pel = peh + (size_t)PEN*HD;     // 131072 sh
  float* d2  = (float*)(pel + (size_t)PEN*HD);    // 8192 f32
  float* qv  = d2 + (size_t)NH*PEN;               // MM*2DM f32 (32 MB)
  unsigned short* hhi = (unsigned short*)(qv + (size_t)MM*2*DM);  // MM*DM
  unsigned short* hlo = hhi + (size_t)MM*DM;                      // MM*DM
  // total = 50,888,704 bytes (proven available)

  hipMemcpyAsync(h, x, (size_t)MM*DM*sizeof(float), hipMemcpyDeviceToDevice, stream);
  split_kernel<<<(MM*DM)/1024, 256, 0, stream>>>(x, hhi, hlo, MM*DM);
  pe_kernel<<<(PEN*HD)/256, 256, 0, stream>>>(peh, pel);

  for (int l = 0; l < NL; ++l) {
    const float* rr_l = rrb + (size_t)l*NH*HD;
    const float* rw_l = rwb + (size_t)l*NH*HD;
    d2_kernel<<<(NH*PEN)/256, 256, 0, stream>>>(rr_l, rw_l, peh, pel, d2);
    // qv (f32) = h @ qv_w^T   [4096 x 2048]
    gemm_mfma<false><<<dim3((2*DM)/128, MM/128), 256, 0, stream>>>(
        hhi, hlo, qv_w + (size_t)l*2*DM*DM, nullptr, qv, 2*DM, DM, 2*DM);
    // fused relative attention -> q-half of qv
    attn_mfma<<<dim3(LL/QT, NH, BB), 256, 0, stream>>>(
        qv, hhi, hlo, peh, pel, rr_l, mask, d2, qv);
    // h = LN1(attn + h), + split
    add_ln_kernel<<<MM, 256, 0, stream>>>(qv, 2*DM, h,
        ln1g + (size_t)l*DM, ln1b + (size_t)l*DM, h, hhi, hlo);
    // ffn out (f32) = relu(h @ ffn_w^T + b) -> v-half of qv
    gemm_mfma<true><<<dim3(DM/128, MM/128), 256, 0, stream>>>(
        hhi, hlo, ffnw + (size_t)l*DM*DM, ffnb + (size_t)l*DM, qv + DM, DM, DM, 2*DM);
    // h = LN2(ffn + h), + split
    add_ln_kernel<<<MM, 256, 0, stream>>>(qv + DM, 2*DM, h,
        ln2g + (size_t)l*DM, ln2b + (size_t)l*DM, h, hhi, hlo);
  }
  (void)in_sizes; (void)n_in; (void)out_size; (void)ws_size;
}

// Round 7
// 1183.005 us; speedup vs baseline: 1.5220x; 1.5220x over previous
//
#include <hip/hip_runtime.h>
#include <math.h>

#define NL 4
#define DM 1024
#define NH 8
#define HD 128
#define BB 8
#define LL 512
#define MM (BB*LL)      // 4096 rows
#define PEN (2*LL)      // 1024 pe rows
#define QT 64           // q rows per attn block
#define KT 32           // k tile
#define NKT (LL/KT)     // 16

typedef __attribute__((ext_vector_type(8))) __bf16 bf16x8;
typedef __attribute__((ext_vector_type(4))) float f32x4;

// ---------------- helpers ----------------
__device__ __forceinline__ unsigned short f2b(float f) {   // RNE f32->bf16
  unsigned int u = __float_as_uint(f);
  u = (u + 0x7FFFu + ((u >> 16) & 1u)) >> 16;
  return (unsigned short)u;
}
__device__ __forceinline__ float b2f(unsigned short s) {
  return __uint_as_float(((unsigned int)s) << 16);
}
__device__ __forceinline__ void glds16(const void* g, void* l) {
  __builtin_amdgcn_global_load_lds(
      (const __attribute__((address_space(1))) unsigned int*)g,
      (__attribute__((address_space(3))) unsigned int*)l, 16, 0, 0);
}
union U8 { unsigned short s[8]; bf16x8 v; };
// trunc-hi / RNE-lo split of 8 floats
__device__ __forceinline__ void split8(const float4& a, const float4& b,
                                       bf16x8& h, bf16x8& l) {
  float x[8] = {a.x,a.y,a.z,a.w,b.x,b.y,b.z,b.w};
  U8 uh, ul;
#pragma unroll
  for (int e = 0; e < 8; ++e) {
    unsigned u = __float_as_uint(x[e]);
    uh.s[e] = (unsigned short)(u >> 16);
    ul.s[e] = f2b(x[e] - __uint_as_float(u & 0xffff0000u));
  }
  h = uh.v; l = ul.v;
}

// -------- relative position embedding (RNE hi + RNE residual lo) ----------
__global__ __launch_bounds__(256) void pe_kernel(unsigned short* __restrict__ peh,
                                                 unsigned short* __restrict__ pel) {
  int idx = blockIdx.x * 256 + threadIdx.x;
  if (idx >= PEN * HD) return;
  int p = idx / HD, j = idx % HD;
  int tt = (j < 64) ? j : (j - 64);
  float invf = expf((float)tt * (-9.210340371976184f / 63.0f));
  float ang = (float)(p - LL) * invf;
  float v = (j < 64) ? sinf(ang) : cosf(ang);
  unsigned short h = f2b(v);
  peh[idx] = h;
  pel[idx] = f2b(v - b2f(h));
}

// ---------------- d2[n][p] = (rw[n]-rr[n]) . pe[p] ----------------
__global__ __launch_bounds__(256) void d2_kernel(const float* __restrict__ rrb,
                                                 const float* __restrict__ rwb,
                                                 const unsigned short* __restrict__ peh,
                                                 const unsigned short* __restrict__ pel,
                                                 float* __restrict__ d2) {
  int idx = blockIdx.x * 256 + threadIdx.x;
  if (idx >= NH * PEN) return;
  int n = idx / PEN, p = idx % PEN;
  float s = 0.f;
  for (int d = 0; d < HD; ++d) {
    float pv = b2f(peh[p*HD + d]) + b2f(pel[p*HD + d]);
    s += (rwb[n*HD + d] - rrb[n*HD + d]) * pv;
  }
  d2[idx] = s;
}

// ---------------- split f32 -> (hi,lo) bf16 pair, RNE ----------------
__global__ __launch_bounds__(256) void split_kernel(const float* __restrict__ in,
                                                    unsigned short* __restrict__ hi,
                                                    unsigned short* __restrict__ lo,
                                                    int n) {
  int i = (blockIdx.x * 256 + threadIdx.x) * 4;
  if (i >= n) return;
  float4 v = *(const float4*)&in[i];
  float x[4] = {v.x, v.y, v.z, v.w};
  ushort4 h4, l4;
  unsigned short* hp = (unsigned short*)&h4;
  unsigned short* lp = (unsigned short*)&l4;
#pragma unroll
  for (int e = 0; e < 4; ++e) {
    unsigned short h = f2b(x[e]);
    hp[e] = h;
    lp[e] = f2b(x[e] - b2f(h));
  }
  *(ushort4*)&hi[i] = h4;
  *(ushort4*)&lo[i] = l4;
}

// ---------------- split-bf16 MFMA GEMM: C = A[M][K] @ Bw[N][K]^T -----------
template<bool FFN>
__global__ __launch_bounds__(256) void gemm_mfma(
    const unsigned short* __restrict__ Ah, const unsigned short* __restrict__ Al,
    const float* __restrict__ Bw, const float* __restrict__ bias,
    float* __restrict__ C, int N, int K, int ldc) {
  __shared__ __align__(16) unsigned short AsH[128*32];
  __shared__ __align__(16) unsigned short AsL[128*32];
  __shared__ __align__(16) unsigned short BsH[128*40];
  __shared__ __align__(16) unsigned short BsL[128*40];
  const int t = threadIdx.x;
  const int w = t >> 6, l = t & 63;
  const int bm = blockIdx.y * 128, bn = blockIdx.x * 128;
  const int wr = (w >> 1) * 64, wc = (w & 1) * 64;

  const unsigned short* Ahb = Ah + (size_t)(bm + (t >> 2)) * K + (t & 3) * 8;
  const unsigned short* Alb = Al + (size_t)(bm + (t >> 2)) * K + (t & 3) * 8;
  unsigned short* AsHw0 = &AsH[w * 512];
  unsigned short* AsHw1 = &AsH[2048 + w * 512];
  unsigned short* AsLw0 = &AsL[w * 512];
  unsigned short* AsLw1 = &AsL[2048 + w * 512];

  const int brow = t >> 1, bhalf = (t & 1) * 16;
  const float* Bb = Bw + (size_t)(bn + brow) * K + bhalf;

  f32x4 acc[4][4] = {};
  const int lm = l & 15;
  const int lk = (l >> 4) * 8;

  for (int k0 = 0; k0 < K; k0 += 32) {
    float4 bv[4];
#pragma unroll
    for (int c = 0; c < 4; ++c)
      bv[c] = *(const float4*)(Bb + k0 + c*4);
    glds16(Ahb + k0,                 AsHw0);
    glds16(Ahb + (size_t)64*K + k0,  AsHw1);
    glds16(Alb + k0,                 AsLw0);
    glds16(Alb + (size_t)64*K + k0,  AsLw1);
#pragma unroll
    for (int c = 0; c < 4; ++c) {
      float xs[4] = {bv[c].x, bv[c].y, bv[c].z, bv[c].w};
      ushort4 h4, l4;
      unsigned short* hp = (unsigned short*)&h4;
      unsigned short* lp = (unsigned short*)&l4;
#pragma unroll
      for (int e = 0; e < 4; ++e) {
        unsigned u = __float_as_uint(xs[e]);
        hp[e] = (unsigned short)(u >> 16);
        float r = xs[e] - __uint_as_float(u & 0xffff0000u);
        lp[e] = (unsigned short)(__float_as_uint(r) >> 16);
      }
      *(ushort4*)&BsH[brow*40 + bhalf + c*4] = h4;
      *(ushort4*)&BsL[brow*40 + bhalf + c*4] = l4;
    }
    __syncthreads();

    bf16x8 afh[4], afl[4], bfh[4], bfl[4];
#pragma unroll
    for (int i = 0; i < 4; ++i) {
      afh[i] = *(const bf16x8*)&AsH[(wr + i*16 + lm) * 32 + lk];
      afl[i] = *(const bf16x8*)&AsL[(wr + i*16 + lm) * 32 + lk];
    }
#pragma unroll
    for (int j = 0; j < 4; ++j) {
      bfh[j] = *(const bf16x8*)&BsH[(wc + j*16 + lm) * 40 + lk];
      bfl[j] = *(const bf16x8*)&BsL[(wc + j*16 + lm) * 40 + lk];
    }
#pragma unroll
    for (int i = 0; i < 4; ++i)
#pragma unroll
      for (int j = 0; j < 4; ++j) {
        acc[i][j] = __builtin_amdgcn_mfma_f32_16x16x32_bf16(afh[i], bfh[j], acc[i][j], 0, 0, 0);
        acc[i][j] = __builtin_amdgcn_mfma_f32_16x16x32_bf16(afh[i], bfl[j], acc[i][j], 0, 0, 0);
        acc[i][j] = __builtin_amdgcn_mfma_f32_16x16x32_bf16(afl[i], bfh[j], acc[i][j], 0, 0, 0);
      }
    __syncthreads();
  }

  const int cr = (l >> 4) * 4;
#pragma unroll
  for (int i = 0; i < 4; ++i) {
#pragma unroll
    for (int j = 0; j < 4; ++j) {
      int row = bm + wr + i*16 + cr;
      int col = bn + wc + j*16 + lm;
      float bvl = FFN ? bias[col] : 0.f;
      f32x4 a = acc[i][j];
#pragma unroll
      for (int r4 = 0; r4 < 4; ++r4) {
        float v = a[r4];
        if (FFN) v = fmaxf(v + bvl, 0.f);
        C[(size_t)(row + r4) * ldc + col] = v;
      }
    }
  }
}

// ================= MFMA fused relative attention (v4) =================
// grid (LL/QT=8, NH, BB), 256 threads = 4 waves; wave w owns q-rows
// [q0+16w, q0+16w+16). logit = qa.k + qa.pe[k-q+512] + d2[n][k-q+512].
// ALL MFMA paths 3-pass split-bf16 (round-4 numerics, absmax 0.031).
// pe streamed from global/L2 (no pe LDS). Padded LDS strides (136/40).
// LDS ~60KB, launch_bounds(256,2): 2 blocks/CU, VGPR cap 256 (no spill).
__global__ __launch_bounds__(256, 2) void attn_mfma(
    const float* __restrict__ qv,           // [MM][2048] f32 (q | v)
    const unsigned short* __restrict__ khp, // keys hi  [MM][1024]
    const unsigned short* __restrict__ klp, // keys lo
    const unsigned short* __restrict__ pehp,// [1024][128] bf16 hi
    const unsigned short* __restrict__ pelp,// [1024][128] bf16 lo
    const float* __restrict__ rrb,          // [NH][128] layer slice
    const int*   __restrict__ mask,         // [BB][LL]
    const float* __restrict__ d2p,          // [NH][1024]
    float* __restrict__ outp)               // = qv (q-half, stride 2048)
{
  __shared__ __align__(16) unsigned short KsH[KT*136];   // 8.5 KB
  __shared__ __align__(16) unsigned short KsL[KT*136];
  __shared__ __align__(16) unsigned short VtH[HD*40];    // 10 KB
  __shared__ __align__(16) unsigned short VtL[HD*40];
  __shared__ float Bsc[4][16*48];                        // 12 KB
  __shared__ __align__(16) unsigned short PsH[4][16*40]; // 5 KB
  __shared__ __align__(16) unsigned short PsL[4][16*40];
  // total ~60 KB -> 2 blocks/CU

  const int q0 = blockIdx.x * QT;
  const int n  = blockIdx.y, b = blockIdx.z;
  const int t  = threadIdx.x;
  const int w  = t >> 6, l = t & 63;
  const int lm = l & 15, lg = l >> 4;
  const int q0w = q0 + w*16;
  const int r8 = t >> 3, s8 = t & 7;        // K staging: row, 16-short seg
  const int vr0 = t >> 5, vd4 = (t & 31)*4; // V staging: row block, dim

  // ---- qa A-frags in registers (split hi/lo) ----
  bf16x8 qah[4], qal[4];
  {
    size_t qrow = (size_t)(b*LL + q0w + lm) * (2*DM) + (size_t)n*HD;
#pragma unroll
    for (int c = 0; c < 4; ++c) {
      int d0 = c*32 + lg*8;
      float4 x1 = *(const float4*)&qv[qrow + d0];
      float4 x2 = *(const float4*)&qv[qrow + d0 + 4];
      float4 r1 = *(const float4*)&rrb[n*HD + d0];
      float4 r2 = *(const float4*)&rrb[n*HD + d0 + 4];
      float4 a = {x1.x+r1.x, x1.y+r1.y, x1.z+r1.z, x1.w+r1.w};
      float4 bq = {x2.x+r2.x, x2.y+r2.y, x2.z+r2.z, x2.w+r2.w};
      split8(a, bq, qah[c], qal[c]);
    }
  }

  // ---- prologue staging: K/V tile 0 ----
  {
    size_t krow = (size_t)(b*LL + r8)*DM + (size_t)n*HD + s8*16;
    *(uint4*)&KsH[r8*136 + s8*16]     = *(const uint4*)&khp[krow];
    *(uint4*)&KsH[r8*136 + s8*16 + 8] = *(const uint4*)&khp[krow + 8];
    *(uint4*)&KsL[r8*136 + s8*16]     = *(const uint4*)&klp[krow];
    *(uint4*)&KsL[r8*136 + s8*16 + 8] = *(const uint4*)&klp[krow + 8];
    // V: thread covers rows vr0*4..+3 at dims vd4..+3 -> b64 transposed writes
    float4 vv[4];
#pragma unroll
    for (int i = 0; i < 4; ++i)
      vv[i] = *(const float4*)&qv[(size_t)(b*LL + vr0*4 + i)*(2*DM) + DM + n*HD + vd4];
#pragma unroll
    for (int e = 0; e < 4; ++e) {
      float xs[4] = {((const float*)&vv[0])[e], ((const float*)&vv[1])[e],
                     ((const float*)&vv[2])[e], ((const float*)&vv[3])[e]};
      ushort4 h4, l4;
      unsigned short* hp = (unsigned short*)&h4;
      unsigned short* lp = (unsigned short*)&l4;
#pragma unroll
      for (int i = 0; i < 4; ++i) {
        unsigned u = __float_as_uint(xs[i]);
        hp[i] = (unsigned short)(u >> 16);
        lp[i] = f2b(xs[i] - __uint_as_float(u & 0xffff0000u));
      }
      *(ushort4*)&VtH[(vd4+e)*40 + vr0*4] = h4;
      *(ushort4*)&VtL[(vd4+e)*40 + vr0*4] = l4;
    }
  }
  __syncthreads();

  float m_run[4] = {-3.0e38f, -3.0e38f, -3.0e38f, -3.0e38f};
  float l_run[4] = {0.f, 0.f, 0.f, 0.f};
  f32x4 accO[8] = {};

  for (int kt = 0; kt < NKT; ++kt) {
    const int k0 = kt * KT;
    const int base_w = k0 - q0w + 497;

    // ---- A) prefetch K/V tile kt+1 into registers ----
    uint4 kxh0, kxh1, kxl0, kxl1;
    float4 vx[4];
    const bool pf = kt < NKT-1;
    if (pf) {
      size_t krow = (size_t)(b*LL + k0 + KT + r8)*DM + (size_t)n*HD + s8*16;
      kxh0 = *(const uint4*)&khp[krow];     kxh1 = *(const uint4*)&khp[krow + 8];
      kxl0 = *(const uint4*)&klp[krow];     kxl1 = *(const uint4*)&klp[krow + 8];
#pragma unroll
      for (int i = 0; i < 4; ++i)
        vx[i] = *(const float4*)&qv[(size_t)(b*LL + k0 + KT + vr0*4 + i)*(2*DM) + DM + n*HD + vd4];
    }

    // ---- B) compute tile kt ----
    float d2v[3];
#pragma unroll
    for (int jt = 0; jt < 3; ++jt) {
      int di = base_w + jt*16 + lm;
      di = di > PEN-1 ? PEN-1 : di;
      d2v[jt] = d2p[n*PEN + di];
    }
    const int msk0 = mask[b*LL + k0 + lm];
    const int msk1 = mask[b*LL + k0 + 16 + lm];

    // pe-term MFMA (3-pass, B-frags streamed from global/L2) -> Bsc (+d2)
#pragma unroll
    for (int jt = 0; jt < 3; ++jt) {
      int prow = base_w + jt*16 + lm;
      prow = prow > PEN-1 ? PEN-1 : prow;     // clamped row feeds col 47, never read
      const unsigned short* pb = pehp + (size_t)prow*HD + lg*8;
      const unsigned short* ql = pelp + (size_t)prow*HD + lg*8;
      bf16x8 ph[4], pl[4];
#pragma unroll
      for (int c = 0; c < 4; ++c) {
        ph[c] = *(const bf16x8*)(pb + c*32);
        pl[c] = *(const bf16x8*)(ql + c*32);
      }
      f32x4 accB = {};
#pragma unroll
      for (int c = 0; c < 4; ++c) {
        accB = __builtin_amdgcn_mfma_f32_16x16x32_bf16(qah[c], ph[c], accB, 0, 0, 0);
        accB = __builtin_amdgcn_mfma_f32_16x16x32_bf16(qah[c], pl[c], accB, 0, 0, 0);
        accB = __builtin_amdgcn_mfma_f32_16x16x32_bf16(qal[c], ph[c], accB, 0, 0, 0);
      }
#pragma unroll
      for (int r = 0; r < 4; ++r)
        Bsc[w][(lg*4 + r)*48 + jt*16 + lm] = accB[r] + d2v[jt];
    }
    asm volatile("s_waitcnt lgkmcnt(0)" ::: "memory");
    __builtin_amdgcn_sched_barrier(0);

    // AC MFMA (3-pass, full precision)
    f32x4 accA[2] = {};
#pragma unroll
    for (int tt = 0; tt < 2; ++tt)
#pragma unroll
      for (int c = 0; c < 4; ++c) {
        const int krow = tt*16 + lm;
        bf16x8 kfh = *(const bf16x8*)&KsH[krow*136 + (c*4+lg)*8];
        bf16x8 kfl = *(const bf16x8*)&KsL[krow*136 + (c*4+lg)*8];
        accA[tt] = __builtin_amdgcn_mfma_f32_16x16x32_bf16(qah[c], kfh, accA[tt], 0, 0, 0);
        accA[tt] = __builtin_amdgcn_mfma_f32_16x16x32_bf16(qah[c], kfl, accA[tt], 0, 0, 0);
        accA[tt] = __builtin_amdgcn_mfma_f32_16x16x32_bf16(qal[c], kfh, accA[tt], 0, 0, 0);
      }

    // softmax in C-layout (rows lg*4+r, cols lm+16t)
    float s[2][4];
#pragma unroll
    for (int tt = 0; tt < 2; ++tt)
#pragma unroll
      for (int r = 0; r < 4; ++r) {
        int qi = lg*4 + r;
        int kc = tt*16 + lm;
        int j  = kc - qi + 15;
        float v = accA[tt][r] + Bsc[w][qi*48 + j];
        s[tt][r] = ((tt ? msk1 : msk0) == 0) ? -1e30f : v;
      }
    float sc4[4];
#pragma unroll
    for (int r = 0; r < 4; ++r) {
      float mt = fmaxf(s[0][r], s[1][r]);
      mt = fmaxf(mt, __shfl_xor(mt, 1));
      mt = fmaxf(mt, __shfl_xor(mt, 2));
      mt = fmaxf(mt, __shfl_xor(mt, 4));
      mt = fmaxf(mt, __shfl_xor(mt, 8));
      float mn = fmaxf(m_run[r], mt);
      sc4[r] = __expf(m_run[r] - mn);
      m_run[r] = mn;
      float p0 = __expf(s[0][r] - mn);
      float p1 = __expf(s[1][r] - mn);
      s[0][r] = p0; s[1][r] = p1;
      float la = p0 + p1;
      la += __shfl_xor(la, 1);
      la += __shfl_xor(la, 2);
      la += __shfl_xor(la, 4);
      la += __shfl_xor(la, 8);
      l_run[r] = l_run[r]*sc4[r] + la;
    }
#pragma unroll
    for (int j8 = 0; j8 < 8; ++j8)
#pragma unroll
      for (int r = 0; r < 4; ++r)
        accO[j8][r] *= sc4[r];

    // P -> split bf16 in LDS (trunc hi / RNE lo; A-frag layout)
#pragma unroll
    for (int tt = 0; tt < 2; ++tt)
#pragma unroll
      for (int r = 0; r < 4; ++r) {
        int qi = lg*4 + r, kc = tt*16 + lm;
        float p = s[tt][r];
        unsigned u = __float_as_uint(p);
        PsH[w][qi*40 + kc] = (unsigned short)(u >> 16);
        PsL[w][qi*40 + kc] = f2b(p - __uint_as_float(u & 0xffff0000u));
      }
    asm volatile("s_waitcnt lgkmcnt(0)" ::: "memory");
    __builtin_amdgcn_sched_barrier(0);

    // PV MFMA (3-pass)
    {
      bf16x8 pah = *(const bf16x8*)&PsH[w][lm*40 + lg*8];
      bf16x8 pal = *(const bf16x8*)&PsL[w][lm*40 + lg*8];
#pragma unroll
      for (int j8 = 0; j8 < 8; ++j8) {
        const int dim = j8*16 + lm;
        bf16x8 vfh = *(const bf16x8*)&VtH[dim*40 + lg*8];
        bf16x8 vfl = *(const bf16x8*)&VtL[dim*40 + lg*8];
        accO[j8] = __builtin_amdgcn_mfma_f32_16x16x32_bf16(pah, vfh, accO[j8], 0, 0, 0);
        accO[j8] = __builtin_amdgcn_mfma_f32_16x16x32_bf16(pah, vfl, accO[j8], 0, 0, 0);
        accO[j8] = __builtin_amdgcn_mfma_f32_16x16x32_bf16(pal, vfh, accO[j8], 0, 0, 0);
      }
    }

    __syncthreads();   // all waves done reading Ks/Vt

    // ---- C) write staged tile kt+1 ----
    if (pf) {
      *(uint4*)&KsH[r8*136 + s8*16]     = kxh0;
      *(uint4*)&KsH[r8*136 + s8*16 + 8] = kxh1;
      *(uint4*)&KsL[r8*136 + s8*16]     = kxl0;
      *(uint4*)&KsL[r8*136 + s8*16 + 8] = kxl1;
#pragma unroll
      for (int e = 0; e < 4; ++e) {
        float xs[4] = {((const float*)&vx[0])[e], ((const float*)&vx[1])[e],
                       ((const float*)&vx[2])[e], ((const float*)&vx[3])[e]};
        ushort4 h4, l4;
        unsigned short* hp = (unsigned short*)&h4;
        unsigned short* lp = (unsigned short*)&l4;
#pragma unroll
        for (int i = 0; i < 4; ++i) {
          unsigned u = __float_as_uint(xs[i]);
          hp[i] = (unsigned short)(u >> 16);
          lp[i] = f2b(xs[i] - __uint_as_float(u & 0xffff0000u));
        }
        *(ushort4*)&VtH[(vd4+e)*40 + vr0*4] = h4;
        *(ushort4*)&VtL[(vd4+e)*40 + vr0*4] = l4;
      }
    }
    __syncthreads();
  }

  // ---- epilogue: O / l  ->  q-half of qv ----
  float inv[4];
#pragma unroll
  for (int r = 0; r < 4; ++r) inv[r] = 1.0f / l_run[r];
#pragma unroll
  for (int j8 = 0; j8 < 8; ++j8)
#pragma unroll
    for (int r = 0; r < 4; ++r)
      outp[(size_t)(b*LL + q0w + lg*4 + r)*(2*DM) + n*HD + j8*16 + lm] = accO[j8][r] * inv[r];
}

// ------- residual add + layernorm (+ split hi/lo bf16 for next GEMM) -------
__global__ __launch_bounds__(256) void add_ln_kernel(
    const float* __restrict__ y, int ys,
    const float* __restrict__ res,
    const float* __restrict__ g, const float* __restrict__ bt,
    float* __restrict__ out,
    unsigned short* __restrict__ ohi, unsigned short* __restrict__ olo)
{
  const int r = blockIdx.x, t = threadIdx.x;
  float4 v = *(const float4*)&y[(size_t)r*ys + t*4];
  float4 w = *(const float4*)&res[(size_t)r*DM + t*4];
  float4 s = {v.x+w.x, v.y+w.y, v.z+w.z, v.w+w.w};
  float sum = s.x + s.y + s.z + s.w;
  float ssq = s.x*s.x + s.y*s.y + s.z*s.z + s.w*s.w;
#pragma unroll
  for (int off = 32; off >= 1; off >>= 1) {
    sum += __shfl_down(sum, off);
    ssq += __shfl_down(ssq, off);
  }
  __shared__ float red[8];
  int wid = t >> 6;
  if ((t & 63) == 0) { red[wid] = sum; red[wid+4] = ssq; }
  __syncthreads();
  float totS = red[0] + red[1] + red[2] + red[3];
  float totQ = red[4] + red[5] + red[6] + red[7];
  float mu  = totS * (1.0f/DM);
  float var = totQ * (1.0f/DM) - mu*mu;
  float inv = rsqrtf(var + 1e-5f);
  float4 gg = *(const float4*)&g[t*4];
  float4 bb = *(const float4*)&bt[t*4];
  float4 o;
  o.x = (s.x - mu)*inv*gg.x + bb.x;
  o.y = (s.y - mu)*inv*gg.y + bb.y;
  o.z = (s.z - mu)*inv*gg.z + bb.z;
  o.w = (s.w - mu)*inv*gg.w + bb.w;
  *(float4*)&out[(size_t)r*DM + t*4] = o;
  float xs[4] = {o.x, o.y, o.z, o.w};
  ushort4 h4, l4;
  unsigned short* hp = (unsigned short*)&h4;
  unsigned short* lp = (unsigned short*)&l4;
#pragma unroll
  for (int e = 0; e < 4; ++e) {
    unsigned short h = f2b(xs[e]);
    hp[e] = h;
    lp[e] = f2b(xs[e] - b2f(h));
  }
  *(ushort4*)&ohi[(size_t)r*DM + t*4] = h4;
  *(ushort4*)&olo[(size_t)r*DM + t*4] = l4;
}

extern "C" void kernel_launch(void* const* d_in, const int* in_sizes, int n_in,
                              void* d_out, int out_size, void* d_ws, size_t ws_size,
                              hipStream_t stream) {
  const float* x    = (const float*)d_in[0];
  const int*   mask = (const int*)d_in[1];
  const float* qv_w = (const float*)d_in[2];
  const float* rrb  = (const float*)d_in[3];
  const float* rwb  = (const float*)d_in[4];
  const float* ln1g = (const float*)d_in[5];
  const float* ln1b = (const float*)d_in[6];
  const float* ffnw = (const float*)d_in[7];
  const float* ffnb = (const float*)d_in[8];
  const float* ln2g = (const float*)d_in[9];
  const float* ln2b = (const float*)d_in[10];

  float* h  = (float*)d_out;                      // [MM][DM] hidden (f32)
  unsigned short* peh = (unsigned short*)d_ws;    // 131072 sh
  unsigned short* pel = peh + (size_t)PEN*HD;     // 131072 sh
  float* d2  = (float*)(pel + (size_t)PEN*HD);    // 8192 f32
  float* qv  = d2 + (size_t)NH*PEN;               // MM*2DM f32 (32 MB)
  unsigned short* hhi = (unsigned short*)(qv + (size_t)MM*2*DM);  // MM*DM
  unsigned short* hlo = hhi + (size_t)MM*DM;                      // MM*DM
  // total = 50,888,704 bytes (proven available)

  hipMemcpyAsync(h, x, (size_t)MM*DM*sizeof(float), hipMemcpyDeviceToDevice, stream);
  split_kernel<<<(MM*DM)/1024, 256, 0, stream>>>(x, hhi, hlo, MM*DM);
  pe_kernel<<<(PEN*HD)/256, 256, 0, stream>>>(peh, pel);

  for (int l = 0; l < NL; ++l) {
    const float* rr_l = rrb + (size_t)l*NH*HD;
    const float* rw_l = rwb + (size_t)l*NH*HD;
    d2_kernel<<<(NH*PEN)/256, 256, 0, stream>>>(rr_l, rw_l, peh, pel, d2);
    // qv (f32) = h @ qv_w^T   [4096 x 2048]
    gemm_mfma<false><<<dim3((2*DM)/128, MM/128), 256, 0, stream>>>(
        hhi, hlo, qv_w + (size_t)l*2*DM*DM, nullptr, qv, 2*DM, DM, 2*DM);
    // fused relative attention -> q-half of qv
    attn_mfma<<<dim3(LL/QT, NH, BB), 256, 0, stream>>>(
        qv, hhi, hlo, peh, pel, rr_l, mask, d2, qv);
    // h = LN1(attn + h), + split
    add_ln_kernel<<<MM, 256, 0, stream>>>(qv, 2*DM, h,
        ln1g + (size_t)l*DM, ln1b + (size_t)l*DM, h, hhi, hlo);
    // ffn out (f32) = relu(h @ ffn_w^T + b) -> v-half of qv
    gemm_mfma<true><<<dim3(DM/128, MM/128), 256, 0, stream>>>(
        hhi, hlo, ffnw + (size_t)l*DM*DM, ffnb + (size_t)l*DM, qv + DM, DM, DM, 2*DM);
    // h = LN2(ffn + h), + split
    add_ln_kernel<<<MM, 256, 0, stream>>>(qv + DM, 2*DM, h,
        ln2g + (size_t)l*DM, ln2b + (size_t)l*DM, h, hhi, hlo);
  }
  (void)in_sizes; (void)n_in; (void)out_size; (void)ws_size;
}